// Round 1
// baseline (183.165 us; speedup 1.0000x reference)
//
#include <hip/hip_runtime.h>
#include <hip/hip_bf16.h>

// Problem constants (from reference): B=256, L=64, C=256, HW=32*32=1024
#define B_  256
#define L_  64
#define C_  256
#define HW_ 1024

typedef float  floatx4 __attribute__((ext_vector_type(4)));
typedef __bf16 bf16x8  __attribute__((ext_vector_type(8)));
typedef __bf16 bf16x4  __attribute__((ext_vector_type(4)));

#define LDT 72   // LDS row stride in bf16 elems (64 + 8 pad -> 144 B, 16B-aligned rows)

// One block: 128x128 tile of group l's GEMM  out_l[256x1024] = A_l[256x256] @ W_l[256x1024]
// 256 threads = 4 waves (2x2), each wave computes 64x64 via 4x4 mfma_f32_16x16x32_bf16.
__global__ __launch_bounds__(256, 3)
void gld_mfma_kernel(const float* __restrict__ code,
                     const float* __restrict__ W,
                     float* __restrict__ out)
{
    const int tid = threadIdx.x;
    const int l   = blockIdx.z;
    const int m0  = blockIdx.y * 128;   // batch rows
    const int n0  = blockIdx.x * 128;   // HW cols

    __shared__ __bf16 Alds[128 * LDT];  // A tile [m][k], bf16
    __shared__ __bf16 Blds[128 * LDT];  // B tile transposed [n][k], bf16

    const int lane = tid & 63;
    const int wave = tid >> 6;
    const int wm = (wave >> 1) * 64;    // wave row offset in tile
    const int wn = (wave & 1)  * 64;    // wave col offset in tile

    floatx4 acc[4][4];
    #pragma unroll
    for (int i = 0; i < 4; ++i)
        #pragma unroll
        for (int j = 0; j < 4; ++j)
            acc[i][j] = (floatx4)0.0f;

    // staging decomposition
    const int a_row = tid >> 4;         // 0..15 (16 rows per pass, 8 passes)
    const int a_kc  = (tid & 15) * 4;   // k-chunk of 4 floats
    const int b_n   = tid & 127;        // column handled by this thread
    const int b_k0  = (tid >> 7) * 4;   // 0 or 4

    const float* codeBase = code + (size_t)m0 * (L_ * C_) + (size_t)l * C_;
    const float* wBase    = W    + (size_t)l * (C_ * HW_) + n0;

    for (int kb = 0; kb < C_; kb += 64) {
        // ---- stage A: 128 rows x 64 k, coalesced float4, convert to bf16 ----
        #pragma unroll
        for (int p = 0; p < 8; ++p) {
            const int row = p * 16 + a_row;
            const floatx4 v = *(const floatx4*)(codeBase + (size_t)row * (L_ * C_) + kb + a_kc);
            bf16x4 h;
            h.x = (__bf16)v.x; h.y = (__bf16)v.y; h.z = (__bf16)v.z; h.w = (__bf16)v.w;
            *(bf16x4*)&Alds[row * LDT + a_kc] = h;
        }
        // ---- stage B transposed: 64 k x 128 n. Lane owns one n, grabs 4 consecutive k
        //      (coalesced across lanes at each k), packs -> one 8B LDS write. ----
        #pragma unroll
        for (int cc = 0; cc < 8; ++cc) {
            const int k = b_k0 + cc * 8;            // covers k=0..63 across threads
            const float* p0 = wBase + (size_t)(kb + k) * HW_ + b_n;
            const float f0 = p0[0 * HW_];
            const float f1 = p0[1 * HW_];
            const float f2 = p0[2 * HW_];
            const float f3 = p0[3 * HW_];
            bf16x4 h;
            h.x = (__bf16)f0; h.y = (__bf16)f1; h.z = (__bf16)f2; h.w = (__bf16)f3;
            *(bf16x4*)&Blds[b_n * LDT + k] = h;
        }
        __syncthreads();

        // ---- compute: 2 k-steps of 32, 16 MFMAs each ----
        #pragma unroll
        for (int ks = 0; ks < 2; ++ks) {
            bf16x8 af[4], bfr[4];
            const int koff = ks * 32 + (lane >> 4) * 8;
            #pragma unroll
            for (int i = 0; i < 4; ++i)
                af[i] = *(const bf16x8*)&Alds[(wm + i * 16 + (lane & 15)) * LDT + koff];
            #pragma unroll
            for (int j = 0; j < 4; ++j)
                bfr[j] = *(const bf16x8*)&Blds[(wn + j * 16 + (lane & 15)) * LDT + koff];
            #pragma unroll
            for (int i = 0; i < 4; ++i)
                #pragma unroll
                for (int j = 0; j < 4; ++j)
                    acc[i][j] = __builtin_amdgcn_mfma_f32_16x16x32_bf16(af[i], bfr[j], acc[i][j], 0, 0, 0);
        }
        __syncthreads();
    }

    // ---- epilogue: C/D layout col=lane&15, row=(lane>>4)*4+reg ----
    const int col0 = lane & 15;
    const int row0 = (lane >> 4) * 4;
    #pragma unroll
    for (int i = 0; i < 4; ++i) {
        #pragma unroll
        for (int j = 0; j < 4; ++j) {
            const int m = m0 + wm + i * 16 + row0;
            const int n = n0 + wn + j * 16 + col0;
            float* o = out + (size_t)m * (L_ * HW_) + (size_t)l * HW_ + n;
            #pragma unroll
            for (int r = 0; r < 4; ++r)
                o[(size_t)r * (L_ * HW_)] = acc[i][j][r];
        }
    }
}

extern "C" void kernel_launch(void* const* d_in, const int* in_sizes, int n_in,
                              void* d_out, int out_size, void* d_ws, size_t ws_size,
                              hipStream_t stream) {
    const float* code = (const float*)d_in[0];   // [256, 64, 256] fp32
    const float* W    = (const float*)d_in[1];   // [64, 256, 1024] fp32
    float* out        = (float*)d_out;           // [256, 64, 32, 32] fp32

    dim3 grid(HW_ / 128, B_ / 128, L_);          // (8, 2, 64)
    gld_mfma_kernel<<<grid, 256, 0, stream>>>(code, W, out);
}

// Round 2
// 140.864 us; speedup vs baseline: 1.3003x; 1.3003x over previous
//
#include <hip/hip_runtime.h>
#include <hip/hip_bf16.h>

// Problem: out[b,l,:] = code[b,l,:] @ W[l]   (B=256, L=64, C=256, HW=1024, fp32)
#define B_  256
#define L_  64
#define C_  256
#define HW_ 1024

typedef float  floatx4 __attribute__((ext_vector_type(4)));
typedef __bf16 bf16x8  __attribute__((ext_vector_type(8)));
typedef __bf16 bf16x4  __attribute__((ext_vector_type(4)));

#define LDT 72   // LDS row stride in bf16 elems (144 B, 16B-aligned rows)

// Barrier that does NOT drain outstanding global loads (vmcnt): only LDS ops
// must be visible across the barrier; register prefetch stays in flight.
#define BARRIER_LDS() asm volatile("s_waitcnt lgkmcnt(0)\n\ts_barrier" ::: "memory")

// One block: 128x128 tile of group l. 512 threads = 8 waves (2x4),
// each wave 64x32 via 4x2 grid of mfma_f32_16x16x32_bf16.
// K-loop software-pipelined: global->reg prefetch of iter k+1 issued before
// the MFMA phase of iter k; barriers don't wait on vmcnt.
__global__ __launch_bounds__(512, 4)
void gld_mfma_kernel(const float* __restrict__ code,
                     const float* __restrict__ W,
                     float* __restrict__ out)
{
    const int tid = threadIdx.x;
    const int l   = blockIdx.z;
    const int m0  = blockIdx.y * 128;   // batch rows
    const int n0  = blockIdx.x * 128;   // HW cols

    __shared__ __bf16 Alds[128 * LDT];  // A tile [m][k] bf16
    __shared__ __bf16 Blds[128 * LDT];  // B tile transposed [n][k] bf16

    const int lane = tid & 63;
    const int wave = tid >> 6;          // 0..7
    const int wm = (wave >> 2) * 64;    // 0,64
    const int wn = (wave & 3) * 32;     // 0,32,64,96

    floatx4 acc[4][2];
    #pragma unroll
    for (int i = 0; i < 4; ++i)
        #pragma unroll
        for (int j = 0; j < 2; ++j)
            acc[i][j] = (floatx4)0.0f;

    // A staging: 128 rows x 64 k fp32 -> 4 float4 per thread
    const int a_row = tid >> 4;          // 0..31 (4 passes of 32 rows)
    const int a_kc  = (tid & 15) * 4;    // k-chunk
    // B staging: 64 k x 128 n fp32, 4x4 micro-tile register transpose
    const int b_nt = (tid & 31) * 4;     // 0..124 (adjacent lanes -> adjacent n)
    const int b_kt = (tid >> 5) * 4;     // 0..60

    const float* aBase = code + (size_t)m0 * (L_ * C_) + (size_t)l * C_ + a_kc;
    const float* wBase = W + (size_t)l * (C_ * HW_) + (size_t)b_kt * HW_ + n0 + b_nt;

    floatx4 Areg[4], Breg[4];

    // ---- prologue: load kb=0 into registers ----
    #pragma unroll
    for (int p = 0; p < 4; ++p)
        Areg[p] = *(const floatx4*)(aBase + (size_t)(p * 32 + a_row) * (L_ * C_));
    #pragma unroll
    for (int i = 0; i < 4; ++i)
        Breg[i] = *(const floatx4*)(wBase + (size_t)i * HW_);

    #pragma unroll
    for (int kb = 0; kb < C_; kb += 64) {
        // ---- stage registers -> LDS (convert fp32 -> bf16) ----
        #pragma unroll
        for (int p = 0; p < 4; ++p) {
            bf16x4 h;
            h.x = (__bf16)Areg[p].x; h.y = (__bf16)Areg[p].y;
            h.z = (__bf16)Areg[p].z; h.w = (__bf16)Areg[p].w;
            *(bf16x4*)&Alds[(p * 32 + a_row) * LDT + a_kc] = h;
        }
        #pragma unroll
        for (int j = 0; j < 4; ++j) {
            bf16x4 h;
            h.x = (__bf16)Breg[0][j]; h.y = (__bf16)Breg[1][j];
            h.z = (__bf16)Breg[2][j]; h.w = (__bf16)Breg[3][j];
            *(bf16x4*)&Blds[(b_nt + j) * LDT + b_kt] = h;
        }

        // ---- issue prefetch for kb+64; stays in flight across the barrier
        //      and the whole MFMA phase ----
        if (kb + 64 < C_) {
            #pragma unroll
            for (int p = 0; p < 4; ++p)
                Areg[p] = *(const floatx4*)(aBase + (size_t)(p * 32 + a_row) * (L_ * C_) + (kb + 64));
            #pragma unroll
            for (int i = 0; i < 4; ++i)
                Breg[i] = *(const floatx4*)(wBase + (size_t)(kb + 64 + i) * HW_);
        }

        BARRIER_LDS();   // LDS writes visible; vmcnt NOT drained

        // ---- compute: 2 k-steps of 32 ----
        #pragma unroll
        for (int ks = 0; ks < 2; ++ks) {
            bf16x8 af[4], bfr[2];
            const int koff = ks * 32 + (lane >> 4) * 8;
            #pragma unroll
            for (int i = 0; i < 4; ++i)
                af[i] = *(const bf16x8*)&Alds[(wm + i * 16 + (lane & 15)) * LDT + koff];
            #pragma unroll
            for (int j = 0; j < 2; ++j)
                bfr[j] = *(const bf16x8*)&Blds[(wn + j * 16 + (lane & 15)) * LDT + koff];
            #pragma unroll
            for (int i = 0; i < 4; ++i)
                #pragma unroll
                for (int j = 0; j < 2; ++j)
                    acc[i][j] = __builtin_amdgcn_mfma_f32_16x16x32_bf16(af[i], bfr[j], acc[i][j], 0, 0, 0);
        }

        BARRIER_LDS();   // all waves done reading before next overwrite
    }

    // ---- epilogue: C/D layout col=lane&15, row=(lane>>4)*4+reg ----
    const int col0 = lane & 15;
    const int row0 = (lane >> 4) * 4;
    #pragma unroll
    for (int i = 0; i < 4; ++i) {
        #pragma unroll
        for (int j = 0; j < 2; ++j) {
            const int m = m0 + wm + i * 16 + row0;
            const int n = n0 + wn + j * 16 + col0;
            float* o = out + (size_t)m * (L_ * HW_) + (size_t)l * HW_ + n;
            #pragma unroll
            for (int r = 0; r < 4; ++r)
                o[(size_t)r * (L_ * HW_)] = acc[i][j][r];
        }
    }
}

extern "C" void kernel_launch(void* const* d_in, const int* in_sizes, int n_in,
                              void* d_out, int out_size, void* d_ws, size_t ws_size,
                              hipStream_t stream) {
    const float* code = (const float*)d_in[0];   // [256, 64, 256] fp32
    const float* W    = (const float*)d_in[1];   // [64, 256, 1024] fp32
    float* out        = (float*)d_out;           // [256, 64, 32, 32] fp32

    dim3 grid(HW_ / 128, B_ / 128, L_);          // (8, 2, 64)
    gld_mfma_kernel<<<grid, 512, 0, stream>>>(code, W, out);
}